// Round 1
// baseline (1210.839 us; speedup 1.0000x reference)
//
#include <hip/hip_runtime.h>
#include <hip/hip_bf16.h>

typedef __bf16 bf16x8 __attribute__((ext_vector_type(8)));
typedef float  f32x4  __attribute__((ext_vector_type(4)));

__device__ __forceinline__ unsigned short f2bf(float f) {
  __bf16 h = (__bf16)f;
  return __builtin_bit_cast(unsigned short, h);
}

// ---------------------------------------------------------------------------
// Weight prep: round to int, repack.
//   w0p  : f32  [tap75][oc192]           (tap = ci*25 + ky*5 + kx)
//   w1p/2: bf16 [tap25][oc192][ci192]
//   w3p  : bf16 [tap25][oc320][ci192]
// Also zeroes the 512B zbuf used as the padding-read target.
// ---------------------------------------------------------------------------
__global__ __launch_bounds__(256) void prep_weights(
    const float* __restrict__ w0, const float* __restrict__ w1,
    const float* __restrict__ w2, const float* __restrict__ w3,
    float* __restrict__ w0p, unsigned short* __restrict__ w1p,
    unsigned short* __restrict__ w2p, unsigned short* __restrict__ w3p,
    unsigned short* __restrict__ zbuf)
{
  if (blockIdx.x == 0 && threadIdx.x < 64)
    ((unsigned long long*)zbuf)[threadIdx.x] = 0ULL;
  const int R0 = 75 * 192;          // 14400
  const int R1 = 25 * 192 * 192;    // 921600
  const int R3 = 25 * 320 * 192;    // 1536000
  const int total = R0 + 2 * R1 + R3;
  for (int i = blockIdx.x * blockDim.x + threadIdx.x; i < total;
       i += gridDim.x * blockDim.x) {
    if (i < R0) {
      int tap = i / 192, oc = i - tap * 192;
      int ci = tap / 25, kk = tap - ci * 25;
      w0p[i] = rintf(w0[(oc * 3 + ci) * 25 + kk]);
    } else if (i < R0 + R1) {
      int j = i - R0;
      int tap = j / 36864; int r = j - tap * 36864;
      int oc = r / 192;    int ci = r - oc * 192;
      w1p[j] = f2bf(rintf(w1[(oc * 192 + ci) * 25 + tap]));
    } else if (i < R0 + 2 * R1) {
      int j = i - R0 - R1;
      int tap = j / 36864; int r = j - tap * 36864;
      int oc = r / 192;    int ci = r - oc * 192;
      w2p[j] = f2bf(rintf(w2[(oc * 192 + ci) * 25 + tap]));
    } else {
      int j = i - R0 - 2 * R1;
      int tap = j / 61440; int r = j - tap * 61440;
      int oc = r / 192;    int ci = r - oc * 192;
      w3p[j] = f2bf(rintf(w3[(oc * 192 + ci) * 25 + tap]));
    }
  }
}

// ---------------------------------------------------------------------------
// Layer 0: Cin=3, 512x512 -> 256x256, 192 oc.  VALU direct conv.
// Block: (b, oy, 64-ox strip). 256 thr = 16 xslot x 16 ocgrp; thread: 4 ox x 12 oc.
// Writes act1 channels-last bf16 [b][oy][ox][oc].
// ---------------------------------------------------------------------------
__global__ __launch_bounds__(256) void conv0(
    const float* __restrict__ x, const float* __restrict__ w0p,
    const float* __restrict__ b0, const float* __restrict__ mul0,
    const int* __restrict__ reluP, const int* __restrict__ mdP,
    unsigned short* __restrict__ act1)
{
  __shared__ float wlds[75 * 192];      // 57600 B
  __shared__ float ilds[3][5][132];     // 7920 B  (total 65520 <= 64KB)
  const int tid = threadIdx.x;
  const int blk = blockIdx.x;
  const int oxblk = blk & 3;
  const int oy = (blk >> 2) & 255;
  const int b = blk >> 10;
  const int oxbase = oxblk * 64;

  for (int i = tid; i < 75 * 192; i += 256) wlds[i] = w0p[i];
  for (int i = tid; i < 3 * 5 * 131; i += 256) {
    int c = i % 131; int t = i / 131; int r = t % 5; int ci = t / 5;
    int iy = 2 * oy - 2 + r;
    int ix = 2 * oxbase - 2 + c;
    float v = 0.0f;
    if ((unsigned)iy < 512u && (unsigned)ix < 512u) {
      float xv = rintf(x[((b * 3 + ci) * 512 + iy) * 512 + ix] * 256.0f);
      v = fminf(fmaxf(xv, 0.0f), 255.0f);
    }
    ilds[ci][r][c] = v;
  }
  __syncthreads();

  const int ocgrp = tid & 15;
  const int xslot = tid >> 4;
  const int oc0 = ocgrp * 12;

  float acc[4][12];
  #pragma unroll
  for (int q = 0; q < 4; q++)
    #pragma unroll
    for (int o = 0; o < 12; o++) acc[q][o] = 0.0f;

  for (int ci = 0; ci < 3; ci++)
    for (int ky = 0; ky < 5; ky++)
      #pragma unroll
      for (int kx = 0; kx < 5; kx++) {
        const float* wr = &wlds[(ci * 25 + ky * 5 + kx) * 192 + oc0];
        float w[12];
        #pragma unroll
        for (int o = 0; o < 12; o++) w[o] = wr[o];
        #pragma unroll
        for (int q = 0; q < 4; q++) {
          float iv = ilds[ci][ky][xslot * 8 + 2 * q + kx];
          #pragma unroll
          for (int o = 0; o < 12; o++) acc[q][o] += iv * w[o];
        }
      }

  // integer epilogue: v=(conv+round(b*256))*mul; >>md0; clip; scl; >>21
  const int rl = reluP[0];
  const int sh = mdP[0];  // md0 + in_scale(8) - clp_k(8)
  const long long clpv = llrint(255.0 / (double)rl * 16777216.0);
  const long long sclv = (long long)((rl + 4) >> 3);
  long long bi[12], mu[12];
  #pragma unroll
  for (int o = 0; o < 12; o++) {
    bi[o] = llrintf(b0[oc0 + o] * 256.0f);
    mu[o] = llrintf(mul0[oc0 + o]);
  }
  for (int q = 0; q < 4; q++) {
    int ox = oxbase + xslot * 4 + q;
    unsigned short pk[12];
    #pragma unroll
    for (int o = 0; o < 12; o++) {
      long long vi = (long long)llrintf(acc[q][o]);
      vi = (vi + bi[o]) * mu[o];
      long long y = (vi + (1LL << (sh - 1))) >> sh;
      y = y < 0 ? 0LL : (y > clpv ? clpv : y);
      y = (y * sclv + (1LL << 20)) >> 21;
      pk[o] = f2bf((float)y);
    }
    size_t base = ((size_t)((b * 256 + oy) * 256 + ox)) * 192 + oc0;
    *(ushort4*)(act1 + base)     = make_ushort4(pk[0], pk[1], pk[2], pk[3]);
    *(ushort4*)(act1 + base + 4) = make_ushort4(pk[4], pk[5], pk[6], pk[7]);
    *(ushort4*)(act1 + base + 8) = make_ushort4(pk[8], pk[9], pk[10], pk[11]);
  }
}

// ---------------------------------------------------------------------------
// Layers 1-3: implicit-GEMM conv, mfma_f32_16x16x32_bf16.
// act channels-last [b][y][x][192]; wp [tap][COUT][CIN].
// Wave tile: FM*16 oc x (16 ox x FN oy) patch. No LDS; A/B frags are 16B
// global loads (8 contiguous ci per lane). Padding reads hit zbuf.
// ---------------------------------------------------------------------------
template <int COUT, int HIN, int WIN, int HOUT, int WOUT, int FM, int FN, int LAYER>
__global__ __launch_bounds__(256) void convN(
    const unsigned short* __restrict__ act,
    const unsigned short* __restrict__ wp,
    const float* __restrict__ bias, const float* __restrict__ mulv,
    const int* __restrict__ reluP, const int* __restrict__ mdP,
    const int* __restrict__ gaP,
    const unsigned short* __restrict__ zbuf,
    unsigned short* __restrict__ outA, float* __restrict__ outF)
{
  constexpr int CIN = 192;
  constexpr int MT = COUT / (FM * 16);
  constexpr int TX = WOUT / 16;
  constexpr int TY = HOUT / FN;
  static_assert(COUT % (FM * 16) == 0 && WOUT % 16 == 0 && HOUT % FN == 0, "tile");

  const int lane = threadIdx.x & 63;
  const int col = lane & 15;
  const int quad = lane >> 4;
  const int gwave = blockIdx.x * (blockDim.x >> 6) + (threadIdx.x >> 6);
  const int m_tile = gwave % MT;
  int nt = gwave / MT;
  const int tx = nt % TX; nt /= TX;
  const int ty = nt % TY;
  const int bb = nt / TY;
  const int m_base = m_tile * (FM * 16);
  const int ox = tx * 16 + col;
  const int oy0 = ty * FN;

  f32x4 acc[FM][FN];
  #pragma unroll
  for (int fm = 0; fm < FM; fm++)
    #pragma unroll
    for (int fn = 0; fn < FN; fn++) acc[fm][fn] = (f32x4){0.f, 0.f, 0.f, 0.f};

  int aoff[FM];
  #pragma unroll
  for (int fm = 0; fm < FM; fm++)
    aoff[fm] = (m_base + fm * 16 + col) * CIN + quad * 8;

  const int abase = bb * HIN * WIN * CIN + quad * 8;
  const unsigned short* zp = zbuf + quad * 8;

  #pragma unroll 1
  for (int ky = 0; ky < 5; ky++) {
    int iy[FN]; bool vy[FN];
    #pragma unroll
    for (int fn = 0; fn < FN; fn++) {
      iy[fn] = 2 * (oy0 + fn) + ky - 2;
      vy[fn] = (unsigned)iy[fn] < (unsigned)HIN;
    }
    #pragma unroll
    for (int kx = 0; kx < 5; kx++) {
      const int ix = 2 * ox + kx - 2;
      const bool vx = (unsigned)ix < (unsigned)WIN;
      const unsigned short* wtap = wp + (ky * 5 + kx) * (COUT * CIN);
      const unsigned short* bp[FN];
      #pragma unroll
      for (int fn = 0; fn < FN; fn++) {
        bool ok = vx && vy[fn];
        bp[fn] = ok ? (act + (abase + (iy[fn] * WIN + ix) * CIN)) : zp;
      }
      #pragma unroll
      for (int cc = 0; cc < CIN / 32; cc++) {
        bf16x8 af[FM], bfr[FN];
        #pragma unroll
        for (int fm = 0; fm < FM; fm++)
          af[fm] = __builtin_bit_cast(bf16x8, *(const uint4*)(wtap + aoff[fm] + cc * 32));
        #pragma unroll
        for (int fn = 0; fn < FN; fn++)
          bfr[fn] = __builtin_bit_cast(bf16x8, *(const uint4*)(bp[fn] + cc * 32));
        #pragma unroll
        for (int fm = 0; fm < FM; fm++)
          #pragma unroll
          for (int fn = 0; fn < FN; fn++)
            acc[fm][fn] = __builtin_amdgcn_mfma_f32_16x16x32_bf16(
                af[fm], bfr[fn], acc[fm][fn], 0, 0, 0);
      }
    }
  }

  // ----- epilogue -----
  if constexpr (LAYER < 3) {
    const int rl = reluP[0];
    const int sh = mdP[0] - 8;  // md - clp_k
    const long long clpv = llrint(255.0 / (double)rl * 16777216.0);
    const long long sclv = (long long)((rl + 4) >> 3);
    #pragma unroll
    for (int fm = 0; fm < FM; fm++) {
      const int oc0 = m_base + fm * 16 + quad * 4;
      long long bi[4], mu[4];
      #pragma unroll
      for (int r = 0; r < 4; r++) {
        bi[r] = llrintf(bias[oc0 + r]);
        mu[r] = llrintf(mulv[oc0 + r]);
      }
      #pragma unroll
      for (int fn = 0; fn < FN; fn++) {
        const int oyv = oy0 + fn;
        unsigned short pk[4];
        #pragma unroll
        for (int r = 0; r < 4; r++) {
          long long vi = (long long)llrintf(acc[fm][fn][r]);
          vi = (vi + bi[r]) * mu[r];
          long long y = (vi + (1LL << (sh - 1))) >> sh;
          y = y < 0 ? 0LL : (y > clpv ? clpv : y);
          y = (y * sclv + (1LL << 20)) >> 21;
          pk[r] = f2bf((float)y);
        }
        *(ushort4*)(outA + ((size_t)((bb * HOUT + oyv) * WOUT + ox)) * COUT + oc0) =
            make_ushort4(pk[0], pk[1], pk[2], pk[3]);
      }
    }
  } else {
    const int sh = mdP[0] - gaP[0];  // md3 - ga_left
    #pragma unroll
    for (int fm = 0; fm < FM; fm++) {
      const int oc0 = m_base + fm * 16 + quad * 4;
      long long bi[4], mu[4];
      #pragma unroll
      for (int r = 0; r < 4; r++) {
        bi[r] = llrintf(bias[oc0 + r]);
        mu[r] = llrintf(mulv[oc0 + r]);
      }
      #pragma unroll
      for (int fn = 0; fn < FN; fn++) {
        const int oyv = oy0 + fn;
        #pragma unroll
        for (int r = 0; r < 4; r++) {
          long long vi = (long long)llrintf(acc[fm][fn][r]);
          vi = (vi + bi[r]) * mu[r];
          long long y = (vi + (1LL << (sh - 1))) >> sh;
          outF[(((size_t)bb * COUT + oc0 + r) * HOUT + oyv) * WOUT + ox] = (float)y;
        }
      }
    }
  }
}

// ---------------------------------------------------------------------------
extern "C" void kernel_launch(void* const* d_in, const int* in_sizes, int n_in,
                              void* d_out, int out_size, void* d_ws, size_t ws_size,
                              hipStream_t stream)
{
  const float* x    = (const float*)d_in[0];
  const float* w0   = (const float*)d_in[1];
  const float* b0   = (const float*)d_in[2];
  const float* w1   = (const float*)d_in[3];
  const float* b1   = (const float*)d_in[4];
  const float* w2   = (const float*)d_in[5];
  const float* b2   = (const float*)d_in[6];
  const float* w3   = (const float*)d_in[7];
  const float* b3   = (const float*)d_in[8];
  const float* mul0 = (const float*)d_in[9];
  const float* mul1 = (const float*)d_in[10];
  const float* mul2 = (const float*)d_in[11];
  const float* mul3 = (const float*)d_in[12];
  const int* relu0  = (const int*)d_in[13];
  const int* relu1  = (const int*)d_in[14];
  const int* relu2  = (const int*)d_in[15];
  const int* md0    = (const int*)d_in[16];
  const int* md1    = (const int*)d_in[17];
  const int* md2    = (const int*)d_in[18];
  const int* md3    = (const int*)d_in[19];
  const int* ga     = (const int*)d_in[20];

  char* ws = (char*)d_ws;
  size_t off = 0;
  unsigned short* zbuf = (unsigned short*)(ws + off); off += 512;
  float*          w0p  = (float*)         (ws + off); off += (size_t)75 * 192 * 4;
  unsigned short* w1p  = (unsigned short*)(ws + off); off += (size_t)25 * 192 * 192 * 2;
  unsigned short* w2p  = (unsigned short*)(ws + off); off += (size_t)25 * 192 * 192 * 2;
  unsigned short* w3p  = (unsigned short*)(ws + off); off += (size_t)25 * 320 * 192 * 2;
  unsigned short* act1 = (unsigned short*)(ws + off); off += (size_t)4 * 256 * 256 * 192 * 2;
  unsigned short* act2 = (unsigned short*)(ws + off); off += (size_t)4 * 128 * 128 * 192 * 2;
  unsigned short* act3 = (unsigned short*)(ws + off); off += (size_t)4 * 64 * 64 * 192 * 2;
  (void)ws_size; (void)in_sizes; (void)n_in; (void)out_size;

  prep_weights<<<2048, 256, 0, stream>>>(w0, w1, w2, w3, w0p, w1p, w2p, w3p, zbuf);
  conv0<<<4096, 256, 0, stream>>>(x, w0p, b0, mul0, relu0, md0, act1);
  // L1: 256x256x192 -> 128x128x192   (3*8*32*4 = 3072 waves)
  convN<192, 256, 256, 128, 128, 4, 4, 1><<<768, 256, 0, stream>>>(
      act1, w1p, b1, mul1, relu1, md1, nullptr, zbuf, act2, nullptr);
  // L2: 128x128x192 -> 64x64x192     (3*4*32*4 = 1536 waves)
  convN<192, 128, 128, 64, 64, 4, 2, 2><<<384, 256, 0, stream>>>(
      act2, w2p, b2, mul2, relu2, md2, nullptr, zbuf, act3, nullptr);
  // L3: 64x64x192 -> 32x32x320       (10*2*16*4 = 1280 waves)
  convN<320, 64, 64, 32, 32, 2, 2, 3><<<320, 256, 0, stream>>>(
      act3, w3p, b3, mul3, nullptr, md3, ga, zbuf, nullptr, (float*)d_out);
}

// Round 2
// 909.189 us; speedup vs baseline: 1.3318x; 1.3318x over previous
//
#include <hip/hip_runtime.h>
#include <hip/hip_bf16.h>

typedef __bf16 bf16x8 __attribute__((ext_vector_type(8)));
typedef float  f32x4  __attribute__((ext_vector_type(4)));
typedef unsigned int u32;

__device__ __forceinline__ unsigned short f2bf(float f) {
  __bf16 h = (__bf16)f;
  return __builtin_bit_cast(unsigned short, h);
}

// async 16B global->LDS copy. LDS dest = wave-uniform base + lane*16.
__device__ __forceinline__ void load_lds16(const void* g, void* l) {
  __builtin_amdgcn_global_load_lds(
      (const __attribute__((address_space(1))) u32*)g,
      (__attribute__((address_space(3))) u32*)l, 16, 0, 0);
}

// ---------------------------------------------------------------------------
// Weight prep.
//   w0p : f32 [tap75][oc192]  (tap = ci*25 + kk) -- for conv0 (unchanged)
//   w1p/w2p (192 oc, MW=3): bf16 packed as the per-step LDS image:
//     [tap25][cc6][mf12][quad4][col16][e8] ; oc=mf*16+col, ci=cc*32+quad*8+e
//   w3p (320 oc, MW=5): same with mf in [0,20).
// Also zeroes the 512B zbuf used as the padding-read target.
// ---------------------------------------------------------------------------
__global__ __launch_bounds__(256) void prep_weights(
    const float* __restrict__ w0, const float* __restrict__ w1,
    const float* __restrict__ w2, const float* __restrict__ w3,
    float* __restrict__ w0p, unsigned short* __restrict__ w1p,
    unsigned short* __restrict__ w2p, unsigned short* __restrict__ w3p,
    unsigned short* __restrict__ zbuf)
{
  if (blockIdx.x == 0 && threadIdx.x < 64)
    ((unsigned long long*)zbuf)[threadIdx.x] = 0ULL;
  const int R0 = 75 * 192;          // 14400
  const int R1 = 25 * 6 * 12 * 4 * 16 * 8;   // 921600
  const int R3 = 25 * 6 * 20 * 4 * 16 * 8;   // 1536000
  const int total = R0 + 2 * R1 + R3;
  for (int i = blockIdx.x * blockDim.x + threadIdx.x; i < total;
       i += gridDim.x * blockDim.x) {
    if (i < R0) {
      int tap = i / 192, oc = i - tap * 192;
      int ci = tap / 25, kk = tap - ci * 25;
      w0p[i] = rintf(w0[(oc * 3 + ci) * 25 + kk]);
    } else if (i < R0 + 2 * R1) {
      int j = i - R0;
      const float* wsrc = w1; unsigned short* wdst = w1p;
      if (j >= R1) { j -= R1; wsrc = w2; wdst = w2p; }
      int e = j & 7, col = (j >> 3) & 15, q = (j >> 7) & 3, t = j >> 9;
      int mf = t % 12; t /= 12; int cc = t % 6; int tap = t / 6;
      int oc = mf * 16 + col, ci = cc * 32 + q * 8 + e;
      wdst[j] = f2bf(rintf(wsrc[(oc * 192 + ci) * 25 + tap]));
    } else {
      int j = i - R0 - 2 * R1;
      int e = j & 7, col = (j >> 3) & 15, q = (j >> 7) & 3, t = j >> 9;
      int mf = t % 20; t /= 20; int cc = t % 6; int tap = t / 6;
      int oc = mf * 16 + col, ci = cc * 32 + q * 8 + e;
      w3p[j] = f2bf(rintf(w3[(oc * 192 + ci) * 25 + tap]));
    }
  }
}

// ---------------------------------------------------------------------------
// Layer 0: Cin=3, 512x512 -> 256x256, 192 oc.  VALU direct conv (unchanged).
// ---------------------------------------------------------------------------
__global__ __launch_bounds__(256) void conv0(
    const float* __restrict__ x, const float* __restrict__ w0p,
    const float* __restrict__ b0, const float* __restrict__ mul0,
    const int* __restrict__ reluP, const int* __restrict__ mdP,
    unsigned short* __restrict__ act1)
{
  __shared__ float wlds[75 * 192];
  __shared__ float ilds[3][5][132];
  const int tid = threadIdx.x;
  const int blk = blockIdx.x;
  const int oxblk = blk & 3;
  const int oy = (blk >> 2) & 255;
  const int b = blk >> 10;
  const int oxbase = oxblk * 64;

  for (int i = tid; i < 75 * 192; i += 256) wlds[i] = w0p[i];
  for (int i = tid; i < 3 * 5 * 131; i += 256) {
    int c = i % 131; int t = i / 131; int r = t % 5; int ci = t / 5;
    int iy = 2 * oy - 2 + r;
    int ix = 2 * oxbase - 2 + c;
    float v = 0.0f;
    if ((unsigned)iy < 512u && (unsigned)ix < 512u) {
      float xv = rintf(x[((b * 3 + ci) * 512 + iy) * 512 + ix] * 256.0f);
      v = fminf(fmaxf(xv, 0.0f), 255.0f);
    }
    ilds[ci][r][c] = v;
  }
  __syncthreads();

  const int ocgrp = tid & 15;
  const int xslot = tid >> 4;
  const int oc0 = ocgrp * 12;

  float acc[4][12];
  #pragma unroll
  for (int q = 0; q < 4; q++)
    #pragma unroll
    for (int o = 0; o < 12; o++) acc[q][o] = 0.0f;

  for (int ci = 0; ci < 3; ci++)
    for (int ky = 0; ky < 5; ky++)
      #pragma unroll
      for (int kx = 0; kx < 5; kx++) {
        const float* wr = &wlds[(ci * 25 + ky * 5 + kx) * 192 + oc0];
        float w[12];
        #pragma unroll
        for (int o = 0; o < 12; o++) w[o] = wr[o];
        #pragma unroll
        for (int q = 0; q < 4; q++) {
          float iv = ilds[ci][ky][xslot * 8 + 2 * q + kx];
          #pragma unroll
          for (int o = 0; o < 12; o++) acc[q][o] += iv * w[o];
        }
      }

  const int rl = reluP[0];
  const int sh = mdP[0];
  const long long clpv = llrint(255.0 / (double)rl * 16777216.0);
  const long long sclv = (long long)((rl + 4) >> 3);
  long long bi[12], mu[12];
  #pragma unroll
  for (int o = 0; o < 12; o++) {
    bi[o] = llrintf(b0[oc0 + o] * 256.0f);
    mu[o] = llrintf(mul0[oc0 + o]);
  }
  for (int q = 0; q < 4; q++) {
    int ox = oxbase + xslot * 4 + q;
    unsigned short pk[12];
    #pragma unroll
    for (int o = 0; o < 12; o++) {
      long long vi = (long long)llrintf(acc[q][o]);
      vi = (vi + bi[o]) * mu[o];
      long long y = (vi + (1LL << (sh - 1))) >> sh;
      y = y < 0 ? 0LL : (y > clpv ? clpv : y);
      y = (y * sclv + (1LL << 20)) >> 21;
      pk[o] = f2bf((float)y);
    }
    size_t base = ((size_t)((b * 256 + oy) * 256 + ox)) * 192 + oc0;
    *(ushort4*)(act1 + base)     = make_ushort4(pk[0], pk[1], pk[2], pk[3]);
    *(ushort4*)(act1 + base + 4) = make_ushort4(pk[4], pk[5], pk[6], pk[7]);
    *(ushort4*)(act1 + base + 8) = make_ushort4(pk[8], pk[9], pk[10], pk[11]);
  }
}

// ---------------------------------------------------------------------------
// Layers 1-3: LDS-staged implicit GEMM (m97-style 2-barrier K-loop).
// Block = MW*NW waves; wave tile = 64 oc x 64 pix (FM=4,FN=4 frags of 16x16x32).
// Block tile: M = MW*64 = COUT (full oc), N = NW*64 pix = 16 ox x NW*4 oy.
// K-loop: 25 taps x 6 cc-chunks of 32 ci = 150 steps. Per step:
//   barrier; async global_load_lds stage A(prepacked image)+B(gather); barrier;
//   8 ds_read_b128 + 16 MFMA per wave.
// ---------------------------------------------------------------------------
template <int COUT, int HIN, int WIN, int HOUT, int WOUT, int MW, int NW, int LAYER>
__global__ __launch_bounds__(MW * NW * 64, 3) void convS(
    const unsigned short* __restrict__ act,
    const unsigned short* __restrict__ wp,
    const float* __restrict__ bias, const float* __restrict__ mulv,
    const int* __restrict__ reluP, const int* __restrict__ mdP,
    const int* __restrict__ gaP,
    const unsigned short* __restrict__ zbuf,
    unsigned short* __restrict__ outA, float* __restrict__ outF)
{
  constexpr int CIN = 192;
  constexpr int NWV = MW * NW;           // waves per block
  constexpr int SAp = MW * 4;            // A staging passes (64 slots each)
  constexpr int PASSES = (MW + NW) * 4;  // total 64-slot passes per step
  constexpr int MAXP = (PASSES + NWV - 1) / NWV;
  constexpr int SAe = MW * 2048;         // A elems per step (MW*64 oc x 32 ci)
  constexpr int LDSB = MW * 4096;        // byte offset of B region
  constexpr int TX = WOUT / 16;
  constexpr int TYB = HOUT / (NW * 4);
  static_assert(MW * 64 == COUT, "M covers COUT");

  __shared__ __align__(16) char smem[PASSES * 1024];

  const int tid = threadIdx.x;
  const int lane = tid & 63;
  const int col = lane & 15;
  const int quad = lane >> 4;
  const int w = tid >> 6;
  const int mw = w % MW;
  const int nw = w / MW;

  int bx = blockIdx.x;
  const int tx = bx % TX; bx /= TX;
  const int ty = bx % TYB;
  const int b = bx / TYB;
  const int ox0 = tx * 16;
  const int oy0 = ty * (NW * 4);

  // ---- per-pass precompute (static across K-steps) ----
  const unsigned short* bptr[MAXP];
  int aoffs[MAXP];
  int bmx[MAXP], bmy[MAXP];
  #pragma unroll
  for (int k = 0; k < MAXP; k++) {
    int p = w + k * NWV;
    if (p >= PASSES) break;
    if (p < SAp) {
      aoffs[k] = (p * 64 + lane) * 8;
      bptr[k] = nullptr; bmx[k] = bmy[k] = 0;
    } else {
      int nf = p - SAp;                 // oy row within tile
      int oxv = ox0 + col;
      int oyv = oy0 + nf;
      bptr[k] = act + ((size_t)b * HIN * WIN + (size_t)(2 * oyv) * WIN + 2 * oxv) * CIN
                + quad * 8;
      int mx = 0, my = 0;
      #pragma unroll
      for (int kk = 0; kk < 5; kk++) {
        if ((unsigned)(2 * oxv + kk - 2) < (unsigned)WIN) mx |= 1 << kk;
        if ((unsigned)(2 * oyv + kk - 2) < (unsigned)HIN) my |= 1 << kk;
      }
      bmx[k] = mx; bmy[k] = my;
    }
  }

  f32x4 acc[4][4];
  #pragma unroll
  for (int fm = 0; fm < 4; fm++)
    #pragma unroll
    for (int fn = 0; fn < 4; fn++) acc[fm][fn] = (f32x4){0.f, 0.f, 0.f, 0.f};

  const char* pA = smem + (mw * 4096 + lane * 16);
  const char* pB = smem + (LDSB + nw * 4096 + lane * 16);

  // ---- K loop: 25 taps x 6 cc ----
  int step = 0;
  for (int tap = 0; tap < 25; tap++) {
    const int ky = tap / 5, kx = tap % 5;
    for (int cc = 0; cc < 6; cc++, step++) {
      const unsigned short* wstep = wp + (size_t)step * SAe;
      const int offB = ((ky - 2) * WIN + (kx - 2)) * CIN + cc * 32;

      __syncthreads();   // previous compute done reading LDS
      #pragma unroll
      for (int k = 0; k < MAXP; k++) {
        int p = w + k * NWV;
        if (p >= PASSES) break;
        void* ldst = smem + p * 1024;
        if (p < SAp) {
          load_lds16(wstep + aoffs[k], ldst);
        } else {
          bool v = ((bmx[k] >> kx) & 1) && ((bmy[k] >> ky) & 1);
          const unsigned short* g = v ? (bptr[k] + offB) : zbuf;
          load_lds16(g, ldst);
        }
      }
      __syncthreads();   // staging drained (vmcnt0 before barrier)

      bf16x8 afr[4], bfr[4];
      #pragma unroll
      for (int i = 0; i < 4; i++)
        afr[i] = __builtin_bit_cast(bf16x8, *(const uint4*)(pA + i * 1024));
      #pragma unroll
      for (int i = 0; i < 4; i++)
        bfr[i] = __builtin_bit_cast(bf16x8, *(const uint4*)(pB + i * 1024));
      #pragma unroll
      for (int fm = 0; fm < 4; fm++)
        #pragma unroll
        for (int fn = 0; fn < 4; fn++)
          acc[fm][fn] = __builtin_amdgcn_mfma_f32_16x16x32_bf16(
              afr[fm], bfr[fn], acc[fm][fn], 0, 0, 0);
    }
  }

  // ---- epilogue ----
  if constexpr (LAYER < 3) {
    const int rl = reluP[0];
    const int sh = mdP[0] - 8;
    const long long clpv = llrint(255.0 / (double)rl * 16777216.0);
    const long long sclv = (long long)((rl + 4) >> 3);
    #pragma unroll
    for (int fm = 0; fm < 4; fm++) {
      const int oc0 = mw * 64 + fm * 16 + quad * 4;
      long long bi[4], mu[4];
      #pragma unroll
      for (int r = 0; r < 4; r++) {
        bi[r] = llrintf(bias[oc0 + r]);
        mu[r] = llrintf(mulv[oc0 + r]);
      }
      #pragma unroll
      for (int fn = 0; fn < 4; fn++) {
        const int oyv = oy0 + nw * 4 + fn;
        const int oxv = ox0 + col;
        unsigned short pk[4];
        #pragma unroll
        for (int r = 0; r < 4; r++) {
          long long vi = (long long)llrintf(acc[fm][fn][r]);
          vi = (vi + bi[r]) * mu[r];
          long long y = (vi + (1LL << (sh - 1))) >> sh;
          y = y < 0 ? 0LL : (y > clpv ? clpv : y);
          y = (y * sclv + (1LL << 20)) >> 21;
          pk[r] = f2bf((float)y);
        }
        *(ushort4*)(outA + ((size_t)((b * HOUT + oyv) * WOUT + oxv)) * COUT + oc0) =
            make_ushort4(pk[0], pk[1], pk[2], pk[3]);
      }
    }
  } else {
    const int sh = mdP[0] - gaP[0];
    #pragma unroll
    for (int fm = 0; fm < 4; fm++) {
      const int oc0 = mw * 64 + fm * 16 + quad * 4;
      long long bi[4], mu[4];
      #pragma unroll
      for (int r = 0; r < 4; r++) {
        bi[r] = llrintf(bias[oc0 + r]);
        mu[r] = llrintf(mulv[oc0 + r]);
      }
      #pragma unroll
      for (int fn = 0; fn < 4; fn++) {
        const int oyv = oy0 + nw * 4 + fn;
        const int oxv = ox0 + col;
        #pragma unroll
        for (int r = 0; r < 4; r++) {
          long long vi = (long long)llrintf(acc[fm][fn][r]);
          vi = (vi + bi[r]) * mu[r];
          long long y = (vi + (1LL << (sh - 1))) >> sh;
          outF[(((size_t)b * COUT + oc0 + r) * HOUT + oyv) * WOUT + oxv] = (float)y;
        }
      }
    }
  }
}

// ---------------------------------------------------------------------------
extern "C" void kernel_launch(void* const* d_in, const int* in_sizes, int n_in,
                              void* d_out, int out_size, void* d_ws, size_t ws_size,
                              hipStream_t stream)
{
  const float* x    = (const float*)d_in[0];
  const float* w0   = (const float*)d_in[1];
  const float* b0   = (const float*)d_in[2];
  const float* w1   = (const float*)d_in[3];
  const float* b1   = (const float*)d_in[4];
  const float* w2   = (const float*)d_in[5];
  const float* b2   = (const float*)d_in[6];
  const float* w3   = (const float*)d_in[7];
  const float* b3   = (const float*)d_in[8];
  const float* mul0 = (const float*)d_in[9];
  const float* mul1 = (const float*)d_in[10];
  const float* mul2 = (const float*)d_in[11];
  const float* mul3 = (const float*)d_in[12];
  const int* relu0  = (const int*)d_in[13];
  const int* relu1  = (const int*)d_in[14];
  const int* relu2  = (const int*)d_in[15];
  const int* md0    = (const int*)d_in[16];
  const int* md1    = (const int*)d_in[17];
  const int* md2    = (const int*)d_in[18];
  const int* md3    = (const int*)d_in[19];
  const int* ga     = (const int*)d_in[20];

  char* ws = (char*)d_ws;
  size_t off = 0;
  unsigned short* zbuf = (unsigned short*)(ws + off); off += 512;
  float*          w0p  = (float*)         (ws + off); off += (size_t)75 * 192 * 4;
  unsigned short* w1p  = (unsigned short*)(ws + off); off += (size_t)25 * 6 * 192 * 32 * 2;
  unsigned short* w2p  = (unsigned short*)(ws + off); off += (size_t)25 * 6 * 192 * 32 * 2;
  unsigned short* w3p  = (unsigned short*)(ws + off); off += (size_t)25 * 6 * 320 * 32 * 2;
  unsigned short* act1 = (unsigned short*)(ws + off); off += (size_t)4 * 256 * 256 * 192 * 2;
  unsigned short* act2 = (unsigned short*)(ws + off); off += (size_t)4 * 128 * 128 * 192 * 2;
  unsigned short* act3 = (unsigned short*)(ws + off); off += (size_t)4 * 64 * 64 * 192 * 2;
  (void)ws_size; (void)in_sizes; (void)n_in; (void)out_size;

  prep_weights<<<2048, 256, 0, stream>>>(w0, w1, w2, w3, w0p, w1p, w2p, w3p, zbuf);
  conv0<<<4096, 256, 0, stream>>>(x, w0p, b0, mul0, relu0, md0, act1);
  // L1: 256x256x192 -> 128x128x192 ; tile 192oc x (16x8)pix ; 8*16*4 = 512 blocks
  convS<192, 256, 256, 128, 128, 3, 2, 1><<<512, 384, 0, stream>>>(
      act1, w1p, b1, mul1, relu1, md1, nullptr, zbuf, act2, nullptr);
  // L2: 128x128x192 -> 64x64x192 ; 4*8*4 = 128 blocks
  convS<192, 128, 128, 64, 64, 3, 2, 2><<<128, 384, 0, stream>>>(
      act2, w2p, b2, mul2, relu2, md2, nullptr, zbuf, act3, nullptr);
  // L3: 64x64x192 -> 32x32x320 ; tile 320oc x (16x4)pix ; 2*8*4 = 64 blocks
  convS<320, 64, 64, 32, 32, 5, 1, 3><<<64, 320, 0, stream>>>(
      act3, w3p, b3, mul3, nullptr, md3, ga, zbuf, nullptr, (float*)d_out);
}

// Round 3
// 552.587 us; speedup vs baseline: 2.1912x; 1.6453x over previous
//
#include <hip/hip_runtime.h>
#include <hip/hip_bf16.h>

typedef int i32x4 __attribute__((ext_vector_type(4)));
typedef unsigned int u32;
typedef long long ll;

// async 16B global->LDS copy. LDS dest = wave-uniform base + lane*16.
__device__ __forceinline__ void load_lds16(const void* g, void* l) {
  __builtin_amdgcn_global_load_lds(
      (const __attribute__((address_space(1))) u32*)g,
      (__attribute__((address_space(3))) u32*)l, 16, 0, 0);
}

// ---------------------------------------------------------------------------
// Weight prep: round to int, repack to i8.
//   w0p : f32 [tap75][oc192]  (tap = ci*25 + kk) -- for conv0
//   wNp : i8 per-step LDS image: [tap25][ch3][mf(M/16)][quad4][col16][e16]
//         oc = mf*16+col, ci = ch*64 + quad*16 + e
// zbuf filled with 0x80 (= -128 as i8): padded B values become (0 - 128).
// ---------------------------------------------------------------------------
template <int MF>
__device__ __forceinline__ void pack_i8(int j, const float* wsrc, signed char* wdst, int CIN) {
  int e = j & 15, col = (j >> 4) & 15, q = (j >> 8) & 3, t = j >> 10;
  int mf = t % MF; t /= MF; int ch = t % 3; int tap = t / 3;
  int oc = mf * 16 + col, ci = ch * 64 + q * 16 + e;
  wdst[j] = (signed char)(int)rintf(wsrc[(oc * CIN + ci) * 25 + tap]);
}

__global__ __launch_bounds__(256) void prep_weights(
    const float* __restrict__ w0, const float* __restrict__ w1,
    const float* __restrict__ w2, const float* __restrict__ w3,
    float* __restrict__ w0p, signed char* __restrict__ w1p,
    signed char* __restrict__ w2p, signed char* __restrict__ w3p,
    signed char* __restrict__ zbuf)
{
  if (blockIdx.x == 0 && threadIdx.x < 128)
    ((unsigned long long*)zbuf)[threadIdx.x] = 0x8080808080808080ULL;
  const int R0 = 75 * 192;                   // 14400 floats
  const int R1 = 25 * 3 * 12 * 1024;         // 921600  (192 oc)
  const int R3 = 25 * 3 * 20 * 1024;         // 1536000 (320 oc)
  const int total = R0 + 2 * R1 + R3;
  for (int i = blockIdx.x * blockDim.x + threadIdx.x; i < total;
       i += gridDim.x * blockDim.x) {
    if (i < R0) {
      int tap = i / 192, oc = i - tap * 192;
      int ci = tap / 25, kk = tap - ci * 25;
      w0p[i] = rintf(w0[(oc * 3 + ci) * 25 + kk]);
    } else if (i < R0 + R1) {
      pack_i8<12>(i - R0, w1, w1p, 192);
    } else if (i < R0 + 2 * R1) {
      pack_i8<12>(i - R0 - R1, w2, w2p, 192);
    } else {
      pack_i8<20>(i - R0 - 2 * R1, w3, w3p, 192);
    }
  }
}

// totw[oc] = sum of rounded weights over all (ci,tap) — the +128 correction.
// thread t: oc = t>>4 (0..703), q = t&15 sums 300 contiguous elems, atomicAdd.
__global__ __launch_bounds__(256) void prep_sums(
    const float* __restrict__ w1, const float* __restrict__ w2,
    const float* __restrict__ w3, int* __restrict__ totw1,
    int* __restrict__ totw2, int* __restrict__ totw3)
{
  int t = blockIdx.x * blockDim.x + threadIdx.x;
  if (t >= 704 * 16) return;
  int oc = t >> 4, q = t & 15;
  const float* ws; int* tot; int o = oc;
  if (oc < 192)      { ws = w1; tot = totw1; }
  else if (oc < 384) { ws = w2; tot = totw2; o = oc - 192; }
  else               { ws = w3; tot = totw3; o = oc - 384; }
  const float* p = ws + (size_t)o * 4800 + q * 300;
  int s = 0;
  #pragma unroll 4
  for (int j = 0; j < 300; j++) s += (int)rintf(p[j]);
  atomicAdd(&tot[o], s);
}

// ---------------------------------------------------------------------------
// Layer 0: Cin=3, 512x512 -> 256x256, 192 oc.  VALU fp32 direct conv.
// Writes act1 channels-last i8 (value - 128).
// ---------------------------------------------------------------------------
__global__ __launch_bounds__(256) void conv0(
    const float* __restrict__ x, const float* __restrict__ w0p,
    const float* __restrict__ b0, const float* __restrict__ mul0,
    const int* __restrict__ reluP, const int* __restrict__ mdP,
    unsigned char* __restrict__ act1)
{
  __shared__ float wlds[75 * 192];
  __shared__ float ilds[3][5][132];
  const int tid = threadIdx.x;
  const int blk = blockIdx.x;
  const int oxblk = blk & 3;
  const int oy = (blk >> 2) & 255;
  const int b = blk >> 10;
  const int oxbase = oxblk * 64;

  for (int i = tid; i < 75 * 192; i += 256) wlds[i] = w0p[i];
  for (int i = tid; i < 3 * 5 * 131; i += 256) {
    int c = i % 131; int t = i / 131; int r = t % 5; int ci = t / 5;
    int iy = 2 * oy - 2 + r;
    int ix = 2 * oxbase - 2 + c;
    float v = 0.0f;
    if ((unsigned)iy < 512u && (unsigned)ix < 512u) {
      float xv = rintf(x[((b * 3 + ci) * 512 + iy) * 512 + ix] * 256.0f);
      v = fminf(fmaxf(xv, 0.0f), 255.0f);
    }
    ilds[ci][r][c] = v;
  }
  __syncthreads();

  const int ocgrp = tid & 15;
  const int xslot = tid >> 4;
  const int oc0 = ocgrp * 12;

  float acc[4][12];
  #pragma unroll
  for (int q = 0; q < 4; q++)
    #pragma unroll
    for (int o = 0; o < 12; o++) acc[q][o] = 0.0f;

  for (int ci = 0; ci < 3; ci++)
    for (int ky = 0; ky < 5; ky++)
      #pragma unroll
      for (int kx = 0; kx < 5; kx++) {
        const float* wr = &wlds[(ci * 25 + ky * 5 + kx) * 192 + oc0];
        float w[12];
        #pragma unroll
        for (int o = 0; o < 12; o++) w[o] = wr[o];
        #pragma unroll
        for (int q = 0; q < 4; q++) {
          float iv = ilds[ci][ky][xslot * 8 + 2 * q + kx];
          #pragma unroll
          for (int o = 0; o < 12; o++) acc[q][o] += iv * w[o];
        }
      }

  const int rl = reluP[0];
  const int sh = mdP[0];  // md0 + in_scale(8) - clp_k(8)
  const ll clpv = llrint(255.0 / (double)rl * 16777216.0);
  const ll sclv = (ll)((rl + 4) >> 3);
  ll bi[12], mu[12];
  #pragma unroll
  for (int o = 0; o < 12; o++) {
    bi[o] = llrintf(b0[oc0 + o] * 256.0f);
    mu[o] = llrintf(mul0[oc0 + o]);
  }
  for (int q = 0; q < 4; q++) {
    int ox = oxbase + xslot * 4 + q;
    u32 wd[3] = {0, 0, 0};
    #pragma unroll
    for (int o = 0; o < 12; o++) {
      ll vi = (ll)llrintf(acc[q][o]);
      vi = (vi + bi[o]) * mu[o];
      ll y = (vi + (1LL << (sh - 1))) >> sh;
      y = y < 0 ? 0LL : (y > clpv ? clpv : y);
      y = (y * sclv + (1LL << 20)) >> 21;          // y in [0,255]
      wd[o >> 2] |= (((u32)y ^ 0x80u) & 0xFFu) << (8 * (o & 3));
    }
    size_t base = ((size_t)((b * 256 + oy) * 256 + ox)) * 192 + oc0;
    *(u32*)(act1 + base)     = wd[0];
    *(u32*)(act1 + base + 4) = wd[1];
    *(u32*)(act1 + base + 8) = wd[2];
  }
}

// ---------------------------------------------------------------------------
// Layers 1-3: LDS-staged implicit GEMM, mfma_i32_16x16x64_i8 (2-barrier K-loop).
// act i8 channels-last, value = x-128 (zbuf pads = -128 keep this uniform;
// the 128*totw correction is folded into the bias at the epilogue).
// Wave tile 64oc x 64pix; block M = MW*64 = COUT, N = 16ox x NW*4 oy.
// K-loop: KSPLIT parts x (25/KSPLIT taps) x 3 chunks of 64 ci.
// DIRECT: integer epilogue -> i8 act out.  else: raw i32 partial store.
// ---------------------------------------------------------------------------
template <int COUT, int HIN, int WIN, int HOUT, int WOUT, int MW, int NW,
          int KSPLIT, bool DIRECT>
__global__ __launch_bounds__(MW * NW * 64, 3) void convS(
    const signed char* __restrict__ act, const signed char* __restrict__ wp,
    const float* __restrict__ bias, const float* __restrict__ mulv,
    const int* __restrict__ totw,
    const int* __restrict__ reluP, const int* __restrict__ mdP,
    const signed char* __restrict__ zbuf,
    unsigned char* __restrict__ outA, int* __restrict__ outP)
{
  constexpr int CIN = 192;
  constexpr int NWV = MW * NW;
  constexpr int SAp = MW * 4;            // A passes (1KB each): M/16
  constexpr int PASSES = (MW + NW) * 4;
  constexpr int MAXP = (PASSES + NWV - 1) / NWV;
  constexpr int SAe = MW * 4096;         // A bytes per step: M x 64ci
  constexpr int TX = WOUT / 16;
  constexpr int TYB = HOUT / (NW * 4);
  constexpr int TPP = 25 / KSPLIT;
  constexpr int PSZ = 4 * HOUT * WOUT * COUT;
  static_assert(MW * 64 == COUT, "M covers COUT");

  __shared__ __align__(16) char smem[PASSES * 1024];

  const int tid = threadIdx.x;
  const int lane = tid & 63;
  const int col = lane & 15;
  const int quad = lane >> 4;
  const int w = tid >> 6;
  const int mw = w % MW;
  const int nw = w / MW;
  const int part = blockIdx.y;

  int bx = blockIdx.x;
  const int tx = bx % TX; bx /= TX;
  const int ty = bx % TYB;
  const int b = bx / TYB;
  const int ox0 = tx * 16;
  const int oy0 = ty * (NW * 4);

  // ---- per-pass precompute (static across K-steps) ----
  const signed char* bptr[MAXP];
  int aoffs[MAXP];
  int bmx[MAXP], bmy[MAXP];
  #pragma unroll
  for (int k = 0; k < MAXP; k++) {
    int p = w + k * NWV;
    if (p >= PASSES) break;
    if (p < SAp) {
      aoffs[k] = p * 1024 + lane * 16;
      bptr[k] = nullptr; bmx[k] = bmy[k] = 0;
    } else {
      int nf = p - SAp;
      int oxv = ox0 + col;
      int oyv = oy0 + nf;
      bptr[k] = act + ((size_t)b * HIN * WIN + (size_t)(2 * oyv) * WIN + 2 * oxv) * CIN
                + quad * 16;
      int mx = 0, my = 0;
      #pragma unroll
      for (int kk = 0; kk < 5; kk++) {
        if ((unsigned)(2 * oxv + kk - 2) < (unsigned)WIN) mx |= 1 << kk;
        if ((unsigned)(2 * oyv + kk - 2) < (unsigned)HIN) my |= 1 << kk;
      }
      bmx[k] = mx; bmy[k] = my;
    }
  }

  i32x4 acc[4][4];
  #pragma unroll
  for (int fm = 0; fm < 4; fm++)
    #pragma unroll
    for (int fn = 0; fn < 4; fn++) acc[fm][fn] = (i32x4){0, 0, 0, 0};

  const char* pA = smem + (mw * 4096 + lane * 16);
  const char* pB = smem + (SAp * 1024 + nw * 4096 + lane * 16);

  // ---- K loop ----
  const int tap0 = part * TPP;
  int s = tap0 * 3;
  #pragma unroll 1
  for (int tt = 0; tt < TPP; tt++) {
    const int tap = tap0 + tt;
    const int ky = tap / 5, kx = tap % 5;
    #pragma unroll 1
    for (int ch = 0; ch < 3; ch++, s++) {
      const signed char* wstep = wp + (size_t)s * SAe;
      const int offB = ((ky - 2) * WIN + (kx - 2)) * CIN + ch * 64;

      __syncthreads();
      #pragma unroll
      for (int k = 0; k < MAXP; k++) {
        int p = w + k * NWV;
        if (p >= PASSES) break;
        void* ldst = smem + p * 1024;
        if (p < SAp) {
          load_lds16(wstep + aoffs[k], ldst);
        } else {
          bool v = ((bmx[k] >> kx) & 1) && ((bmy[k] >> ky) & 1);
          const signed char* g = v ? (bptr[k] + offB) : (zbuf + quad * 16);
          load_lds16(g, ldst);
        }
      }
      __syncthreads();

      i32x4 afr[4], bfr[4];
      #pragma unroll
      for (int i = 0; i < 4; i++)
        afr[i] = *(const i32x4*)(pA + i * 1024);
      #pragma unroll
      for (int i = 0; i < 4; i++)
        bfr[i] = *(const i32x4*)(pB + i * 1024);
      #pragma unroll
      for (int fm = 0; fm < 4; fm++)
        #pragma unroll
        for (int fn = 0; fn < 4; fn++)
          acc[fm][fn] = __builtin_amdgcn_mfma_i32_16x16x64_i8(
              afr[fm], bfr[fn], acc[fm][fn], 0, 0, 0);
    }
  }

  // ---- epilogue ----
  if constexpr (DIRECT) {
    const int rl = reluP[0];
    const int sh = mdP[0] - 8;
    const ll clpv = llrint(255.0 / (double)rl * 16777216.0);
    const ll sclv = (ll)((rl + 4) >> 3);
    #pragma unroll
    for (int fm = 0; fm < 4; fm++) {
      const int oc0 = mw * 64 + fm * 16 + quad * 4;
      ll bi[4], mu[4];
      #pragma unroll
      for (int r = 0; r < 4; r++) {
        bi[r] = llrintf(bias[oc0 + r]) + 128LL * totw[oc0 + r];
        mu[r] = llrintf(mulv[oc0 + r]);
      }
      #pragma unroll
      for (int fn = 0; fn < 4; fn++) {
        const int oyv = oy0 + nw * 4 + fn;
        const int oxv = ox0 + col;
        u32 wd = 0;
        #pragma unroll
        for (int r = 0; r < 4; r++) {
          ll vi = ((ll)acc[fm][fn][r] + bi[r]) * mu[r];
          ll y = (vi + (1LL << (sh - 1))) >> sh;
          y = y < 0 ? 0LL : (y > clpv ? clpv : y);
          y = (y * sclv + (1LL << 20)) >> 21;      // [0,255]
          wd |= (((u32)y ^ 0x80u) & 0xFFu) << (8 * r);
        }
        *(u32*)(outA + ((size_t)((b * HOUT + oyv) * WOUT + oxv)) * COUT + oc0) = wd;
      }
    }
  } else {
    int* pout = outP + (size_t)part * PSZ;
    #pragma unroll
    for (int fm = 0; fm < 4; fm++) {
      const int oc0 = mw * 64 + fm * 16 + quad * 4;
      #pragma unroll
      for (int fn = 0; fn < 4; fn++) {
        const int oyv = oy0 + nw * 4 + fn;
        const int oxv = ox0 + col;
        *(i32x4*)(pout + ((size_t)((b * HOUT + oyv) * WOUT + oxv)) * COUT + oc0) =
            acc[fm][fn];
      }
    }
  }
}

// ---------------------------------------------------------------------------
// reduce2: sum 5 L2 partials + integer epilogue -> act3 (i8, channels-last).
// 4 outputs per thread (int4 loads).
// ---------------------------------------------------------------------------
__global__ __launch_bounds__(256) void reduce2(
    const int* __restrict__ partP, const float* __restrict__ bias,
    const float* __restrict__ mulv, const int* __restrict__ totw,
    const int* __restrict__ reluP, const int* __restrict__ mdP,
    unsigned char* __restrict__ outA)
{
  const int gid = blockIdx.x * 256 + threadIdx.x;   // 786432
  const int PSZ4 = 4 * 64 * 64 * 192 / 4;
  const int4* pp = (const int4*)partP;
  int4 sv = pp[gid];
  #pragma unroll
  for (int p = 1; p < 5; p++) {
    int4 v = pp[(size_t)p * PSZ4 + gid];
    sv.x += v.x; sv.y += v.y; sv.z += v.z; sv.w += v.w;
  }
  int sa[4] = {sv.x, sv.y, sv.z, sv.w};
  const int oc0 = (gid * 4) % 192;
  const int rl = reluP[0];
  const int sh = mdP[0] - 8;
  const ll clpv = llrint(255.0 / (double)rl * 16777216.0);
  const ll sclv = (ll)((rl + 4) >> 3);
  u32 wd = 0;
  #pragma unroll
  for (int r = 0; r < 4; r++) {
    ll bi = llrintf(bias[oc0 + r]) + 128LL * totw[oc0 + r];
    ll mu = llrintf(mulv[oc0 + r]);
    ll vi = ((ll)sa[r] + bi) * mu;
    ll y = (vi + (1LL << (sh - 1))) >> sh;
    y = y < 0 ? 0LL : (y > clpv ? clpv : y);
    y = (y * sclv + (1LL << 20)) >> 21;
    wd |= (((u32)y ^ 0x80u) & 0xFFu) << (8 * r);
  }
  ((u32*)outA)[gid] = wd;
}

// ---------------------------------------------------------------------------
// reduce3: sum 5 L3 partials + final shift -> d_out f32 NCHW (coalesced write).
// ---------------------------------------------------------------------------
__global__ __launch_bounds__(256) void reduce3(
    const int* __restrict__ partP, const float* __restrict__ b3,
    const float* __restrict__ mul3, const int* __restrict__ totw3,
    const int* __restrict__ mdP, const int* __restrict__ gaP,
    float* __restrict__ outF)
{
  const int gid = blockIdx.x * 256 + threadIdx.x;   // 1310720
  int t = gid;
  const int ox = t & 31; t >>= 5;
  const int oy = t & 31; t >>= 5;
  const int oc = t % 320;
  const int b  = t / 320;
  const int PSZ = 4 * 32 * 32 * 320;
  const size_t src = ((size_t)((b * 32 + oy) * 32 + ox)) * 320 + oc;
  ll s = 0;
  #pragma unroll
  for (int p = 0; p < 5; p++) s += partP[(size_t)p * PSZ + src];
  const int sh = mdP[0] - gaP[0];
  const ll bi = llrintf(b3[oc]) + 128LL * totw3[oc];
  const ll mu = llrintf(mul3[oc]);
  const ll y = ((s + bi) * mu + (1LL << (sh - 1))) >> sh;
  outF[gid] = (float)y;
}

// ---------------------------------------------------------------------------
extern "C" void kernel_launch(void* const* d_in, const int* in_sizes, int n_in,
                              void* d_out, int out_size, void* d_ws, size_t ws_size,
                              hipStream_t stream)
{
  const float* x    = (const float*)d_in[0];
  const float* w0   = (const float*)d_in[1];
  const float* b0   = (const float*)d_in[2];
  const float* w1   = (const float*)d_in[3];
  const float* b1   = (const float*)d_in[4];
  const float* w2   = (const float*)d_in[5];
  const float* b2   = (const float*)d_in[6];
  const float* w3   = (const float*)d_in[7];
  const float* b3   = (const float*)d_in[8];
  const float* mul0 = (const float*)d_in[9];
  const float* mul1 = (const float*)d_in[10];
  const float* mul2 = (const float*)d_in[11];
  const float* mul3 = (const float*)d_in[12];
  const int* relu0  = (const int*)d_in[13];
  const int* relu1  = (const int*)d_in[14];
  const int* relu2  = (const int*)d_in[15];
  const int* md0    = (const int*)d_in[16];
  const int* md1    = (const int*)d_in[17];
  const int* md2    = (const int*)d_in[18];
  const int* md3    = (const int*)d_in[19];
  const int* ga     = (const int*)d_in[20];

  char* ws = (char*)d_ws;
  size_t off = 0;
  signed char* zbuf = (signed char*)(ws + off); off += 1024;
  float*       w0p  = (float*)      (ws + off); off += (size_t)75 * 192 * 4;
  signed char* w1p  = (signed char*)(ws + off); off += 921600;
  signed char* w2p  = (signed char*)(ws + off); off += 921600;
  signed char* w3p  = (signed char*)(ws + off); off += 1536000;
  int*         totw1= (int*)        (ws + off); off += 192 * 4;
  int*         totw2= (int*)        (ws + off); off += 192 * 4;
  int*         totw3= (int*)        (ws + off); off += 320 * 4;
  unsigned char* act1 = (unsigned char*)(ws + off); off += (size_t)4 * 256 * 256 * 192;
  unsigned char* act2 = (unsigned char*)(ws + off); off += (size_t)4 * 128 * 128 * 192;
  unsigned char* act3 = (unsigned char*)(ws + off); off += (size_t)4 * 64 * 64 * 192;
  int*         partl  = (int*)(ws + off); off += (size_t)5 * 4 * 64 * 64 * 192 * 4; // 62.9MB, shared L2/L3
  (void)ws_size; (void)in_sizes; (void)n_in; (void)out_size;

  hipMemsetAsync(totw1, 0, (192 + 192 + 320) * 4, stream);
  prep_weights<<<2048, 256, 0, stream>>>(w0, w1, w2, w3, w0p, w1p, w2p, w3p, zbuf);
  prep_sums<<<44, 256, 0, stream>>>(w1, w2, w3, totw1, totw2, totw3);
  conv0<<<4096, 256, 0, stream>>>(x, w0p, b0, mul0, relu0, md0, act1);
  // L1: 256x256 -> 128x128x192 ; 512 blocks x 6 waves ; direct epilogue
  convS<192, 256, 256, 128, 128, 3, 2, 1, true><<<dim3(512, 1), 384, 0, stream>>>(
      (const signed char*)act1, w1p, b1, mul1, totw1, relu1, md1, zbuf, act2, nullptr);
  // L2: 128x128 -> 64x64x192 ; split-K 5 -> 640 blocks ; i32 partials
  convS<192, 128, 128, 64, 64, 3, 2, 5, false><<<dim3(128, 5), 384, 0, stream>>>(
      (const signed char*)act2, w2p, b2, mul2, totw2, relu2, md2, zbuf, nullptr, partl);
  reduce2<<<3072, 256, 0, stream>>>(partl, b2, mul2, totw2, relu2, md2, act3);
  // L3: 64x64 -> 32x32x320 ; split-K 5 -> 320 blocks ; i32 partials
  convS<320, 64, 64, 32, 32, 5, 1, 5, false><<<dim3(64, 5), 320, 0, stream>>>(
      (const signed char*)act3, w3p, b3, mul3, totw3, nullptr, md3, zbuf, nullptr, partl);
  reduce3<<<5120, 256, 0, stream>>>(partl, b3, mul3, totw3, md3, ga, (float*)d_out);
}

// Round 4
// 420.290 us; speedup vs baseline: 2.8810x; 1.3148x over previous
//
#include <hip/hip_runtime.h>
#include <hip/hip_bf16.h>

typedef int i32x4 __attribute__((ext_vector_type(4)));
typedef unsigned int u32;
typedef long long ll;

// async 16B global->LDS copy. LDS dest = wave-uniform base + lane*16.
__device__ __forceinline__ void load_lds16(const void* g, void* l) {
  __builtin_amdgcn_global_load_lds(
      (const __attribute__((address_space(1))) u32*)g,
      (__attribute__((address_space(3))) u32*)l, 16, 0, 0);
}

// ---------------------------------------------------------------------------
// Weight prep: round to int, repack to i8.
//   w0q : i8 per-step LDS image for layer0 patch-GEMM (K=128, 2 steps of 64):
//         [ch2][mf12][quad4][col16][e16]; oc=mf*16+col, k=ch*64+quad*16+e,
//         k<75 -> (ci=k/25, tap=k%25), else 0.
//   wNp : i8 per-step LDS image: [tap25][ch3][mf(M/16)][quad4][col16][e16]
//         oc = mf*16+col, ci = ch*64 + quad*16 + e
// zbuf filled with 0x80 (= -128 as i8): padded B values become (0 - 128).
// ---------------------------------------------------------------------------
template <int MF>
__device__ __forceinline__ void pack_i8(int j, const float* wsrc, signed char* wdst, int CIN) {
  int e = j & 15, col = (j >> 4) & 15, q = (j >> 8) & 3, t = j >> 10;
  int mf = t % MF; t /= MF; int ch = t % 3; int tap = t / 3;
  int oc = mf * 16 + col, ci = ch * 64 + q * 16 + e;
  wdst[j] = (signed char)(int)rintf(wsrc[(oc * CIN + ci) * 25 + tap]);
}

__global__ __launch_bounds__(256) void prep_weights(
    const float* __restrict__ w0, const float* __restrict__ w1,
    const float* __restrict__ w2, const float* __restrict__ w3,
    signed char* __restrict__ w0q, signed char* __restrict__ w1p,
    signed char* __restrict__ w2p, signed char* __restrict__ w3p,
    signed char* __restrict__ zbuf)
{
  if (blockIdx.x == 0 && threadIdx.x < 128)
    ((unsigned long long*)zbuf)[threadIdx.x] = 0x8080808080808080ULL;
  const int R0 = 2 * 12 * 1024;              // 24576 (layer0, K padded to 128)
  const int R1 = 25 * 3 * 12 * 1024;         // 921600  (192 oc)
  const int R3 = 25 * 3 * 20 * 1024;         // 1536000 (320 oc)
  const int total = R0 + 2 * R1 + R3;
  for (int i = blockIdx.x * blockDim.x + threadIdx.x; i < total;
       i += gridDim.x * blockDim.x) {
    if (i < R0) {
      int e = i & 15, col = (i >> 4) & 15, q = (i >> 8) & 3, t = i >> 10;
      int mf = t % 12, ch = t / 12;
      int k = ch * 64 + q * 16 + e;
      signed char v = 0;
      if (k < 75) {
        int ci = k / 25, tap = k - ci * 25;
        v = (signed char)(int)rintf(w0[((mf * 16 + col) * 3 + ci) * 25 + tap]);
      }
      w0q[i] = v;
    } else if (i < R0 + R1) {
      pack_i8<12>(i - R0, w1, w1p, 192);
    } else if (i < R0 + 2 * R1) {
      pack_i8<12>(i - R0 - R1, w2, w2p, 192);
    } else {
      pack_i8<20>(i - R0 - 2 * R1, w3, w3p, 192);
    }
  }
}

// totw[oc] = sum of rounded weights over all (ci,tap) — the +128 correction.
// w1/w2/w3: 16 threads per oc, atomicAdd. w0: 1 thread per oc (75 elems).
__global__ __launch_bounds__(256) void prep_sums(
    const float* __restrict__ w0, const float* __restrict__ w1,
    const float* __restrict__ w2, const float* __restrict__ w3,
    int* __restrict__ totw0, int* __restrict__ totw1,
    int* __restrict__ totw2, int* __restrict__ totw3)
{
  int t = blockIdx.x * blockDim.x + threadIdx.x;
  if (t < 704 * 16) {
    int oc = t >> 4, q = t & 15;
    const float* ws; int* tot; int o = oc;
    if (oc < 192)      { ws = w1; tot = totw1; }
    else if (oc < 384) { ws = w2; tot = totw2; o = oc - 192; }
    else               { ws = w3; tot = totw3; o = oc - 384; }
    const float* p = ws + (size_t)o * 4800 + q * 300;
    int s = 0;
    #pragma unroll 4
    for (int j = 0; j < 300; j++) s += (int)rintf(p[j]);
    atomicAdd(&tot[o], s);
  } else {
    int oc = t - 704 * 16;
    if (oc < 192) {
      const float* p = w0 + (size_t)oc * 75;
      int s = 0;
      #pragma unroll 5
      for (int j = 0; j < 75; j++) s += (int)rintf(p[j]);
      totw0[oc] = s;
    }
  }
}

// ---------------------------------------------------------------------------
// quant0: quantize input + im2col -> patch[pix][128] i8 (value-128).
// Block: (b, oy, 64-ox strip). k = ci*25+ky*5+kx for k<75, else 0 bytes.
// Conv zero-padding positions store -128 (true 0 under the -128 offset).
// ---------------------------------------------------------------------------
__global__ __launch_bounds__(256) void quant0(
    const float* __restrict__ x, signed char* __restrict__ patch)
{
  __shared__ signed char ilds[3][5][132];
  const int tid = threadIdx.x;
  const int blk = blockIdx.x;
  const int oxblk = blk & 3;
  const int oy = (blk >> 2) & 255;
  const int b = blk >> 10;
  const int oxbase = oxblk * 64;

  for (int i = tid; i < 3 * 5 * 131; i += 256) {
    int c = i % 131; int t = i / 131; int r = t % 5; int ci = t / 5;
    int iy = 2 * oy - 2 + r;
    int ix = 2 * oxbase - 2 + c;
    int v = -128;
    if ((unsigned)iy < 512u && (unsigned)ix < 512u) {
      float xv = rintf(x[((b * 3 + ci) * 512 + iy) * 512 + ix] * 256.0f);
      xv = fminf(fmaxf(xv, 0.0f), 255.0f);
      v = (int)xv - 128;
    }
    ilds[ci][r][c] = (signed char)v;
  }
  __syncthreads();

  const int px = tid >> 2, part = tid & 3;
  const int xbase = 2 * px;
  u32 res[8];
  #pragma unroll
  for (int wd = 0; wd < 8; wd++) {
    u32 v = 0;
    #pragma unroll
    for (int bb = 0; bb < 4; bb++) {
      int k = part * 32 + wd * 4 + bb;
      u32 byte = 0;
      if (k < 75) {
        int ci = k / 25, rem = k - ci * 25, ky = rem / 5, kx = rem - ky * 5;
        byte = (u32)(unsigned char)ilds[ci][ky][xbase + kx];
      }
      v |= byte << (8 * bb);
    }
    res[wd] = v;
  }
  size_t base = ((size_t)((b * 256 + oy) * 256 + oxbase + px)) * 128 + part * 32;
  *(uint4*)(patch + base)      = make_uint4(res[0], res[1], res[2], res[3]);
  *(uint4*)(patch + base + 16) = make_uint4(res[4], res[5], res[6], res[7]);
}

// ---------------------------------------------------------------------------
// convP: layer0 patch-GEMM. M=192 (MW=3), N=128 px/block, K=128 (2 steps).
// Same staging/MFMA structure as convS; direct integer epilogue -> act1 i8.
// ---------------------------------------------------------------------------
__global__ __launch_bounds__(384, 3) void convP(
    const signed char* __restrict__ patch, const signed char* __restrict__ wq,
    const float* __restrict__ bias, const float* __restrict__ mulv,
    const int* __restrict__ totw,
    const int* __restrict__ reluP, const int* __restrict__ mdP,
    unsigned char* __restrict__ outA)
{
  constexpr int MW = 3, NWAVE = 6;
  constexpr int SAp = 12;
  constexpr int PASSES = 20;
  constexpr int MAXP = 4;
  constexpr int SAe = 12288;
  __shared__ __align__(16) char smem[PASSES * 1024];

  const int tid = threadIdx.x;
  const int lane = tid & 63;
  const int col = lane & 15;
  const int quad = lane >> 4;
  const int w = tid >> 6;
  const int mw = w % MW;
  const int nw = w / MW;
  const int pix0 = blockIdx.x * 128;

  const signed char* bptr[MAXP];
  int aoffs[MAXP];
  #pragma unroll
  for (int k = 0; k < MAXP; k++) {
    int p = w + k * NWAVE;
    if (p >= PASSES) break;
    if (p < SAp) { aoffs[k] = p * 1024 + lane * 16; bptr[k] = nullptr; }
    else {
      int nf = p - SAp;
      bptr[k] = patch + (size_t)(pix0 + nf * 16 + col) * 128 + quad * 16;
    }
  }

  i32x4 acc[4][4];
  #pragma unroll
  for (int fm = 0; fm < 4; fm++)
    #pragma unroll
    for (int fn = 0; fn < 4; fn++) acc[fm][fn] = (i32x4){0, 0, 0, 0};

  const char* pA = smem + (mw * 4096 + lane * 16);
  const char* pB = smem + (SAp * 1024 + nw * 4096 + lane * 16);

  #pragma unroll 1
  for (int ch = 0; ch < 2; ch++) {
    const signed char* wstep = wq + ch * SAe;
    __syncthreads();
    #pragma unroll
    for (int k = 0; k < MAXP; k++) {
      int p = w + k * NWAVE;
      if (p >= PASSES) break;
      void* ldst = smem + p * 1024;
      if (p < SAp) load_lds16(wstep + aoffs[k], ldst);
      else         load_lds16(bptr[k] + ch * 64, ldst);
    }
    __syncthreads();

    i32x4 afr[4], bfr[4];
    #pragma unroll
    for (int i = 0; i < 4; i++) afr[i] = *(const i32x4*)(pA + i * 1024);
    #pragma unroll
    for (int i = 0; i < 4; i++) bfr[i] = *(const i32x4*)(pB + i * 1024);
    #pragma unroll
    for (int fm = 0; fm < 4; fm++)
      #pragma unroll
      for (int fn = 0; fn < 4; fn++)
        acc[fm][fn] = __builtin_amdgcn_mfma_i32_16x16x64_i8(
            afr[fm], bfr[fn], acc[fm][fn], 0, 0, 0);
  }

  // epilogue: layer0 scaling — bias*256, sh = md0 (+in_scale-clp_k = 0 net)
  const int rl = reluP[0];
  const int sh = mdP[0];
  const ll clpv = llrint(255.0 / (double)rl * 16777216.0);
  const ll sclv = (ll)((rl + 4) >> 3);
  #pragma unroll
  for (int fm = 0; fm < 4; fm++) {
    const int oc0 = mw * 64 + fm * 16 + quad * 4;
    ll bi[4], mu[4];
    #pragma unroll
    for (int r = 0; r < 4; r++) {
      bi[r] = llrintf(bias[oc0 + r] * 256.0f) + 128LL * totw[oc0 + r];
      mu[r] = llrintf(mulv[oc0 + r]);
    }
    #pragma unroll
    for (int fn = 0; fn < 4; fn++) {
      const int pix = pix0 + nw * 64 + fn * 16 + col;
      u32 wd = 0;
      #pragma unroll
      for (int r = 0; r < 4; r++) {
        ll vi = ((ll)acc[fm][fn][r] + bi[r]) * mu[r];
        ll y = (vi + (1LL << (sh - 1))) >> sh;
        y = y < 0 ? 0LL : (y > clpv ? clpv : y);
        y = (y * sclv + (1LL << 20)) >> 21;      // [0,255]
        wd |= (((u32)y ^ 0x80u) & 0xFFu) << (8 * r);
      }
      *(u32*)(outA + (size_t)pix * 192 + oc0) = wd;
    }
  }
}

// ---------------------------------------------------------------------------
// Layers 1-3: LDS-staged implicit GEMM, mfma_i32_16x16x64_i8 (2-barrier K-loop).
// act i8 channels-last, value = x-128 (zbuf pads = -128 keep this uniform;
// the 128*totw correction is folded into the bias at the epilogue).
// Wave tile 64oc x 64pix; block M = MW*64 = COUT, N = 16ox x NW*4 oy.
// K-loop: KSPLIT parts x (25/KSPLIT taps) x 3 chunks of 64 ci.
// DIRECT: integer epilogue -> i8 act out.  else: raw i32 partial store.
// ---------------------------------------------------------------------------
template <int COUT, int HIN, int WIN, int HOUT, int WOUT, int MW, int NW,
          int KSPLIT, bool DIRECT>
__global__ __launch_bounds__(MW * NW * 64, 3) void convS(
    const signed char* __restrict__ act, const signed char* __restrict__ wp,
    const float* __restrict__ bias, const float* __restrict__ mulv,
    const int* __restrict__ totw,
    const int* __restrict__ reluP, const int* __restrict__ mdP,
    const signed char* __restrict__ zbuf,
    unsigned char* __restrict__ outA, int* __restrict__ outP)
{
  constexpr int CIN = 192;
  constexpr int NWV = MW * NW;
  constexpr int SAp = MW * 4;            // A passes (1KB each): M/16
  constexpr int PASSES = (MW + NW) * 4;
  constexpr int MAXP = (PASSES + NWV - 1) / NWV;
  constexpr int SAe = MW * 4096;         // A bytes per step: M x 64ci
  constexpr int TX = WOUT / 16;
  constexpr int TYB = HOUT / (NW * 4);
  constexpr int TPP = 25 / KSPLIT;
  constexpr int PSZ = 4 * HOUT * WOUT * COUT;
  static_assert(MW * 64 == COUT, "M covers COUT");

  __shared__ __align__(16) char smem[PASSES * 1024];

  const int tid = threadIdx.x;
  const int lane = tid & 63;
  const int col = lane & 15;
  const int quad = lane >> 4;
  const int w = tid >> 6;
  const int mw = w % MW;
  const int nw = w / MW;
  const int part = blockIdx.y;

  int bx = blockIdx.x;
  const int tx = bx % TX; bx /= TX;
  const int ty = bx % TYB;
  const int b = bx / TYB;
  const int ox0 = tx * 16;
  const int oy0 = ty * (NW * 4);

  // ---- per-pass precompute (static across K-steps) ----
  const signed char* bptr[MAXP];
  int aoffs[MAXP];
  int bmx[MAXP], bmy[MAXP];
  #pragma unroll
  for (int k = 0; k < MAXP; k++) {
    int p = w + k * NWV;
    if (p >= PASSES) break;
    if (p < SAp) {
      aoffs[k] = p * 1024 + lane * 16;
      bptr[k] = nullptr; bmx[k] = bmy[k] = 0;
    } else {
      int nf = p - SAp;
      int oxv = ox0 + col;
      int oyv = oy0 + nf;
      bptr[k] = act + ((size_t)b * HIN * WIN + (size_t)(2 * oyv) * WIN + 2 * oxv) * CIN
                + quad * 16;
      int mx = 0, my = 0;
      #pragma unroll
      for (int kk = 0; kk < 5; kk++) {
        if ((unsigned)(2 * oxv + kk - 2) < (unsigned)WIN) mx |= 1 << kk;
        if ((unsigned)(2 * oyv + kk - 2) < (unsigned)HIN) my |= 1 << kk;
      }
      bmx[k] = mx; bmy[k] = my;
    }
  }

  i32x4 acc[4][4];
  #pragma unroll
  for (int fm = 0; fm < 4; fm++)
    #pragma unroll
    for (int fn = 0; fn < 4; fn++) acc[fm][fn] = (i32x4){0, 0, 0, 0};

  const char* pA = smem + (mw * 4096 + lane * 16);
  const char* pB = smem + (SAp * 1024 + nw * 4096 + lane * 16);

  // ---- K loop ----
  const int tap0 = part * TPP;
  int s = tap0 * 3;
  #pragma unroll 1
  for (int tt = 0; tt < TPP; tt++) {
    const int tap = tap0 + tt;
    const int ky = tap / 5, kx = tap % 5;
    #pragma unroll 1
    for (int ch = 0; ch < 3; ch++, s++) {
      const signed char* wstep = wp + (size_t)s * SAe;
      const int offB = ((ky - 2) * WIN + (kx - 2)) * CIN + ch * 64;

      __syncthreads();
      #pragma unroll
      for (int k = 0; k < MAXP; k++) {
        int p = w + k * NWV;
        if (p >= PASSES) break;
        void* ldst = smem + p * 1024;
        if (p < SAp) {
          load_lds16(wstep + aoffs[k], ldst);
        } else {
          bool v = ((bmx[k] >> kx) & 1) && ((bmy[k] >> ky) & 1);
          const signed char* g = v ? (bptr[k] + offB) : (zbuf + quad * 16);
          load_lds16(g, ldst);
        }
      }
      __syncthreads();

      i32x4 afr[4], bfr[4];
      #pragma unroll
      for (int i = 0; i < 4; i++)
        afr[i] = *(const i32x4*)(pA + i * 1024);
      #pragma unroll
      for (int i = 0; i < 4; i++)
        bfr[i] = *(const i32x4*)(pB + i * 1024);
      #pragma unroll
      for (int fm = 0; fm < 4; fm++)
        #pragma unroll
        for (int fn = 0; fn < 4; fn++)
          acc[fm][fn] = __builtin_amdgcn_mfma_i32_16x16x64_i8(
              afr[fm], bfr[fn], acc[fm][fn], 0, 0, 0);
    }
  }

  // ---- epilogue ----
  if constexpr (DIRECT) {
    const int rl = reluP[0];
    const int sh = mdP[0] - 8;
    const ll clpv = llrint(255.0 / (double)rl * 16777216.0);
    const ll sclv = (ll)((rl + 4) >> 3);
    #pragma unroll
    for (int fm = 0; fm < 4; fm++) {
      const int oc0 = mw * 64 + fm * 16 + quad * 4;
      ll bi[4], mu[4];
      #pragma unroll
      for (int r = 0; r < 4; r++) {
        bi[r] = llrintf(bias[oc0 + r]) + 128LL * totw[oc0 + r];
        mu[r] = llrintf(mulv[oc0 + r]);
      }
      #pragma unroll
      for (int fn = 0; fn < 4; fn++) {
        const int oyv = oy0 + nw * 4 + fn;
        const int oxv = ox0 + col;
        u32 wd = 0;
        #pragma unroll
        for (int r = 0; r < 4; r++) {
          ll vi = ((ll)acc[fm][fn][r] + bi[r]) * mu[r];
          ll y = (vi + (1LL << (sh - 1))) >> sh;
          y = y < 0 ? 0LL : (y > clpv ? clpv : y);
          y = (y * sclv + (1LL << 20)) >> 21;      // [0,255]
          wd |= (((u32)y ^ 0x80u) & 0xFFu) << (8 * r);
        }
        *(u32*)(outA + ((size_t)((b * HOUT + oyv) * WOUT + oxv)) * COUT + oc0) = wd;
      }
    }
  } else {
    int* pout = outP + (size_t)part * PSZ;
    #pragma unroll
    for (int fm = 0; fm < 4; fm++) {
      const int oc0 = mw * 64 + fm * 16 + quad * 4;
      #pragma unroll
      for (int fn = 0; fn < 4; fn++) {
        const int oyv = oy0 + nw * 4 + fn;
        const int oxv = ox0 + col;
        *(i32x4*)(pout + ((size_t)((b * HOUT + oyv) * WOUT + oxv)) * COUT + oc0) =
            acc[fm][fn];
      }
    }
  }
}

// ---------------------------------------------------------------------------
// reduce2: sum 5 L2 partials + integer epilogue -> act3 (i8, channels-last).
// ---------------------------------------------------------------------------
__global__ __launch_bounds__(256) void reduce2(
    const int* __restrict__ partP, const float* __restrict__ bias,
    const float* __restrict__ mulv, const int* __restrict__ totw,
    const int* __restrict__ reluP, const int* __restrict__ mdP,
    unsigned char* __restrict__ outA)
{
  const int gid = blockIdx.x * 256 + threadIdx.x;   // 786432
  const int PSZ4 = 4 * 64 * 64 * 192 / 4;
  const int4* pp = (const int4*)partP;
  int4 sv = pp[gid];
  #pragma unroll
  for (int p = 1; p < 5; p++) {
    int4 v = pp[(size_t)p * PSZ4 + gid];
    sv.x += v.x; sv.y += v.y; sv.z += v.z; sv.w += v.w;
  }
  int sa[4] = {sv.x, sv.y, sv.z, sv.w};
  const int oc0 = (gid * 4) % 192;
  const int rl = reluP[0];
  const int sh = mdP[0] - 8;
  const ll clpv = llrint(255.0 / (double)rl * 16777216.0);
  const ll sclv = (ll)((rl + 4) >> 3);
  u32 wd = 0;
  #pragma unroll
  for (int r = 0; r < 4; r++) {
    ll bi = llrintf(bias[oc0 + r]) + 128LL * totw[oc0 + r];
    ll mu = llrintf(mulv[oc0 + r]);
    ll vi = ((ll)sa[r] + bi) * mu;
    ll y = (vi + (1LL << (sh - 1))) >> sh;
    y = y < 0 ? 0LL : (y > clpv ? clpv : y);
    y = (y * sclv + (1LL << 20)) >> 21;
    wd |= (((u32)y ^ 0x80u) & 0xFFu) << (8 * r);
  }
  ((u32*)outA)[gid] = wd;
}

// ---------------------------------------------------------------------------
// reduce3: sum 5 L3 partials + final shift -> d_out f32 NCHW (coalesced write).
// ---------------------------------------------------------------------------
__global__ __launch_bounds__(256) void reduce3(
    const int* __restrict__ partP, const float* __restrict__ b3,
    const float* __restrict__ mul3, const int* __restrict__ totw3,
    const int* __restrict__ mdP, const int* __restrict__ gaP,
    float* __restrict__ outF)
{
  const int gid = blockIdx.x * 256 + threadIdx.x;   // 1310720
  int t = gid;
  const int ox = t & 31; t >>= 5;
  const int oy = t & 31; t >>= 5;
  const int oc = t % 320;
  const int b  = t / 320;
  const int PSZ = 4 * 32 * 32 * 320;
  const size_t src = ((size_t)((b * 32 + oy) * 32 + ox)) * 320 + oc;
  ll s = 0;
  #pragma unroll
  for (int p = 0; p < 5; p++) s += partP[(size_t)p * PSZ + src];
  const int sh = mdP[0] - gaP[0];
  const ll bi = llrintf(b3[oc]) + 128LL * totw3[oc];
  const ll mu = llrintf(mul3[oc]);
  const ll y = ((s + bi) * mu + (1LL << (sh - 1))) >> sh;
  outF[gid] = (float)y;
}

// ---------------------------------------------------------------------------
extern "C" void kernel_launch(void* const* d_in, const int* in_sizes, int n_in,
                              void* d_out, int out_size, void* d_ws, size_t ws_size,
                              hipStream_t stream)
{
  const float* x    = (const float*)d_in[0];
  const float* w0   = (const float*)d_in[1];
  const float* b0   = (const float*)d_in[2];
  const float* w1   = (const float*)d_in[3];
  const float* b1   = (const float*)d_in[4];
  const float* w2   = (const float*)d_in[5];
  const float* b2   = (const float*)d_in[6];
  const float* w3   = (const float*)d_in[7];
  const float* b3   = (const float*)d_in[8];
  const float* mul0 = (const float*)d_in[9];
  const float* mul1 = (const float*)d_in[10];
  const float* mul2 = (const float*)d_in[11];
  const float* mul3 = (const float*)d_in[12];
  const int* relu0  = (const int*)d_in[13];
  const int* relu1  = (const int*)d_in[14];
  const int* relu2  = (const int*)d_in[15];
  const int* md0    = (const int*)d_in[16];
  const int* md1    = (const int*)d_in[17];
  const int* md2    = (const int*)d_in[18];
  const int* md3    = (const int*)d_in[19];
  const int* ga     = (const int*)d_in[20];

  char* ws = (char*)d_ws;
  size_t off = 0;
  signed char* zbuf = (signed char*)(ws + off); off += 1024;
  signed char* w0q  = (signed char*)(ws + off); off += 24576;
  signed char* w1p  = (signed char*)(ws + off); off += 921600;
  signed char* w2p  = (signed char*)(ws + off); off += 921600;
  signed char* w3p  = (signed char*)(ws + off); off += 1536000;
  int*         totw1= (int*)        (ws + off); off += 192 * 4;
  int*         totw2= (int*)        (ws + off); off += 192 * 4;
  int*         totw3= (int*)        (ws + off); off += 320 * 4;
  int*         totw0= (int*)        (ws + off); off += 192 * 4;
  unsigned char* act1 = (unsigned char*)(ws + off); off += (size_t)4 * 256 * 256 * 192;
  unsigned char* act2 = (unsigned char*)(ws + off); off += (size_t)4 * 128 * 128 * 192;
  unsigned char* act3 = (unsigned char*)(ws + off); off += (size_t)4 * 64 * 64 * 192;
  int*         partl  = (int*)(ws + off); off += (size_t)5 * 4 * 64 * 64 * 192 * 4; // 62.9MB
  signed char* patch  = (signed char*)partl;  // 33.5MB alias, disjoint lifetime
  (void)ws_size; (void)in_sizes; (void)n_in; (void)out_size;

  hipMemsetAsync(totw1, 0, (192 + 192 + 320 + 192) * 4, stream);
  prep_weights<<<2048, 256, 0, stream>>>(w0, w1, w2, w3, w0q, w1p, w2p, w3p, zbuf);
  prep_sums<<<45, 256, 0, stream>>>(w0, w1, w2, w3, totw0, totw1, totw2, totw3);
  // L0: quantize+im2col, then patch-GEMM (M=192, N=262144, K=128)
  quant0<<<4096, 256, 0, stream>>>(x, patch);
  convP<<<2048, 384, 0, stream>>>(patch, w0q, b0, mul0, totw0, relu0, md0, act1);
  // L1: 256x256 -> 128x128x192 ; 512 blocks x 6 waves ; direct epilogue
  convS<192, 256, 256, 128, 128, 3, 2, 1, true><<<dim3(512, 1), 384, 0, stream>>>(
      (const signed char*)act1, w1p, b1, mul1, totw1, relu1, md1, zbuf, act2, nullptr);
  // L2: 128x128 -> 64x64x192 ; split-K 5 -> 640 blocks ; i32 partials
  convS<192, 128, 128, 64, 64, 3, 2, 5, false><<<dim3(128, 5), 384, 0, stream>>>(
      (const signed char*)act2, w2p, b2, mul2, totw2, relu2, md2, zbuf, nullptr, partl);
  reduce2<<<3072, 256, 0, stream>>>(partl, b2, mul2, totw2, relu2, md2, act3);
  // L3: 64x64 -> 32x32x320 ; split-K 5 -> 320 blocks ; i32 partials
  convS<320, 64, 64, 32, 32, 5, 1, 5, false><<<dim3(64, 5), 320, 0, stream>>>(
      (const signed char*)act3, w3p, b3, mul3, totw3, nullptr, md3, zbuf, nullptr, partl);
  reduce3<<<5120, 256, 0, stream>>>(partl, b3, mul3, totw3, md3, ga, (float*)d_out);
}